// Round 3
// baseline (544.400 us; speedup 1.0000x reference)
//
#include <hip/hip_runtime.h>

// ---------------------------------------------------------------------------
// GCN (PyG-style) on MI355X.
//   h = relu(Ahat (h W) + b) x3, then Ahat (h W_out) + b_out, mean-pool.
// R1: hierarchical scan. R2: fusion Ahat(hW)=(Ahat h)W. R3: bf16 activations.
// R4: dis-prescaled activations. R5: padded CSR + paired 16-deep gather.
// R6: MFMA phase B (double-pumped W=Whi+Wlo), rank-based fill.
// R8: no-atomic pooling. R10: proj fused into layer-3.
// R13: projection on MFMA too; aggout+pool merged into k_aggpool.
// R14: phase A 4-rows-per-wave x uint4-per-lane (1 KB/load-instr).
// R15 FAILED (reverted): 2-deep pipeline — MSHR-limited, not ILP-limited.
// R16: shard-ordered CSR. rank computed per (target, src>>12) bucket so each
//     row's neighbors are sorted by source shard (~1MB shards). Concurrent
//     waves sweep the activation table in the same shard order -> gathers hit
//     a moving ~2-3MB window that fits per-XCD L2 (latency ~200cy vs ~600cy
//     L3). Phase A/B unchanged. Also: k_aggpool widened to 1024 threads.
// ---------------------------------------------------------------------------

#define SCAN_BLOCKS 64
#define SCAN_THREADS (SCAN_BLOCKS * 256)   // 16384
#define SHARD_SHIFT 12                      // 4096 rows/shard = 1MB of table

typedef unsigned short u16;
typedef unsigned int   u32;
typedef __attribute__((ext_vector_type(8))) short bf16x8;   // 8 bf16 (4 VGPRs)
typedef __attribute__((ext_vector_type(4))) float f32x4;

static __device__ __forceinline__ u16 f2bf(float x) {
    u32 u = __float_as_uint(x);
    u32 r = (u + 0x7fffu + ((u >> 16) & 1u)) >> 16;   // RNE
    return (u16)r;
}
static __device__ __forceinline__ float bf_lo(u32 p) { return __uint_as_float(p << 16); }
static __device__ __forceinline__ float bf_hi(u32 p) { return __uint_as_float(p & 0xffff0000u); }

// rank within (target, source-shard) bucket -> csr comes out shard-sorted.
__global__ __launch_bounds__(256) void k_count(const int* __restrict__ col,
                                               const int* __restrict__ row,
                                               int E,
                                               int* __restrict__ cnt32, int SH,
                                               u16* __restrict__ rank) {
    int e = blockIdx.x * 256 + threadIdx.x;
    if (e < E) {
        int c = col[e];
        int s = row[e] >> SHARD_SHIFT;
        rank[e] = (u16)atomicAdd(&cnt32[c * SH + s], 1);
    }
}

__global__ __launch_bounds__(256) void k_scan1(const int* __restrict__ cnt32, int SH,
                                               int* __restrict__ tsum, int N) {
    int t = blockIdx.x * 256 + threadIdx.x;
    int strip = (N + SCAN_THREADS - 1) / SCAN_THREADS;
    int s0 = t * strip;
    int s1 = s0 + strip; if (s1 > N) s1 = N;
    int s = 0;
    for (int i = s0; i < s1; ++i) {
        int tot = 0;
        for (int q = 0; q < SH; ++q) tot += cnt32[i * SH + q];
        s += (tot + 3) & ~3;
    }
    tsum[t] = s;
}

__global__ __launch_bounds__(1024) void k_scan2(int* __restrict__ tsum) {
    __shared__ int part[1024];
    int t = threadIdx.x;
    int base = t * 16;
    int local[16];
    int s = 0;
    #pragma unroll
    for (int i = 0; i < 16; ++i) { local[i] = tsum[base + i]; s += local[i]; }
    part[t] = s;
    __syncthreads();
    for (int off = 1; off < 1024; off <<= 1) {
        int v = part[t];
        int add = (t >= off) ? part[t - off] : 0;
        __syncthreads();
        part[t] = v + add;
        __syncthreads();
    }
    int run = (t == 0) ? 0 : part[t - 1];
    #pragma unroll
    for (int i = 0; i < 16; ++i) { int c = local[i]; tsum[base + i] = run; run += c; }
}

// rowptr + per-(row,shard) segment bases + pads + dis.
__global__ __launch_bounds__(256) void k_scan3(const int* __restrict__ cnt32, int SH,
                                               const int* __restrict__ tsum,
                                               int* __restrict__ rowptr,
                                               int* __restrict__ segbase,
                                               float* __restrict__ dis,
                                               int* __restrict__ csr, int N) {
    int t = blockIdx.x * 256 + threadIdx.x;
    int strip = (N + SCAN_THREADS - 1) / SCAN_THREADS;
    int s0 = t * strip;
    int s1 = s0 + strip; if (s1 > N) s1 = N;
    int run = tsum[t];
    for (int i = s0; i < s1; ++i) {
        rowptr[i] = run;
        int acc = 0;
        for (int q = 0; q < SH; ++q) {
            segbase[i * SH + q] = run + acc;
            acc += cnt32[i * SH + q];
        }
        int c = acc;
        int r = (c + 3) & ~3;
        for (int p = run + c; p < run + r; ++p) csr[p] = N;   // pads -> zero row
        run += r;
        dis[i] = rsqrtf((float)(c + 1));
    }
    if (t == SCAN_THREADS - 1) rowptr[N] = run;
}

// Scatter without atomics: rank captured during k_count (per (col,shard)).
__global__ __launch_bounds__(256) void k_fill(const int* __restrict__ row,
                                              const int* __restrict__ col, int E,
                                              const int* __restrict__ segbase, int SH,
                                              const u16* __restrict__ rank,
                                              int* __restrict__ csr) {
    int e = blockIdx.x * 256 + threadIdx.x;
    if (e < E) {
        int c = col[e];
        int src = row[e];
        int s = src >> SHARD_SHIFT;
        csr[segbase[c * SH + s] + (int)rank[e]] = src;
    }
}

// fp32 -> bf16 cast pre-scaled by dis[v]; also zeroes dummy row N of all bufs.
__global__ __launch_bounds__(256) void k_cast(const float* __restrict__ src,
                                              const float* __restrict__ dis,
                                              u16* __restrict__ bX,
                                              u16* __restrict__ bA,
                                              u16* __restrict__ bB, int N) {
    int i = blockIdx.x * 256 + threadIdx.x;   // float4-group index over N+1 rows
    int total = (N + 1) * 32;
    if (i >= total) return;
    int v = i >> 5;
    if (v < N) {
        float dv = dis[v];
        float4 val = ((const float4*)src)[i];
        ushort4 o;
        o.x = f2bf(dv * val.x); o.y = f2bf(dv * val.y);
        o.z = f2bf(dv * val.z); o.w = f2bf(dv * val.w);
        ((ushort4*)bX)[i] = o;
    } else {
        ushort4 z = {0, 0, 0, 0};
        ((ushort4*)bX)[i] = z;
        ((ushort4*)bA)[i] = z;
        ((ushort4*)bB)[i] = z;
    }
}

// Pre-swizzle weights into MFMA B-fragment order, split hi+lo bf16.
// Blocks 0..23: the three 128x128 W (8 blocks each). Block 24: Wout 128xC
// zero-padded to 16 cols, stored at uint4 offset 6144.
__global__ __launch_bounds__(256) void k_wprep4(const float* __restrict__ W0,
                                                const float* __restrict__ W1,
                                                const float* __restrict__ W2,
                                                const float* __restrict__ Wo,
                                                u32* __restrict__ whi,
                                                u32* __restrict__ wlo, int C) {
    if (blockIdx.x < 24) {
        int which = blockIdx.x >> 3;
        const float* W = (which == 0) ? W0 : (which == 1) ? W1 : W2;
        int t = (blockIdx.x & 7) * 256 + threadIdx.x;   // 0..2047
        int lane = t & 63;
        int nk = t >> 6;
        int k0 = nk & 3;
        int ntile = nk >> 2;
        int n = ntile * 16 + (lane & 15);
        int kbase = k0 * 32 + (lane >> 4) * 8;
        u32 hi[4], lo[4];
        #pragma unroll
        for (int tt = 0; tt < 4; ++tt) {
            float w0 = W[(kbase + 2 * tt) * 128 + n];
            float w1 = W[(kbase + 2 * tt + 1) * 128 + n];
            u16 h0 = f2bf(w0), h1 = f2bf(w1);
            u16 l0 = f2bf(w0 - __uint_as_float((u32)h0 << 16));
            u16 l1 = f2bf(w1 - __uint_as_float((u32)h1 << 16));
            hi[tt] = (u32)h0 | ((u32)h1 << 16);
            lo[tt] = (u32)l0 | ((u32)l1 << 16);
        }
        uint4 qh = {hi[0], hi[1], hi[2], hi[3]};
        uint4 ql = {lo[0], lo[1], lo[2], lo[3]};
        int base = which * 2048;
        ((uint4*)whi)[base + t] = qh;
        ((uint4*)wlo)[base + t] = ql;
    } else {
        int t = threadIdx.x;       // 0..255 == k0*64 + lane
        int lane = t & 63;
        int k0 = t >> 6;
        int n = lane & 15;
        int kbase = k0 * 32 + (lane >> 4) * 8;
        bool vc = (n < C);
        u32 hi[4], lo[4];
        #pragma unroll
        for (int tt = 0; tt < 4; ++tt) {
            float w0 = vc ? Wo[(kbase + 2 * tt) * C + n] : 0.f;
            float w1 = vc ? Wo[(kbase + 2 * tt + 1) * C + n] : 0.f;
            u16 h0 = f2bf(w0), h1 = f2bf(w1);
            u16 l0 = f2bf(w0 - __uint_as_float((u32)h0 << 16));
            u16 l1 = f2bf(w1 - __uint_as_float((u32)h1 << 16));
            hi[tt] = (u32)h0 | ((u32)h1 << 16);
            lo[tt] = (u32)l0 | ((u32)l1 << 16);
        }
        uint4 qh = {hi[0], hi[1], hi[2], hi[3]};
        uint4 ql = {lo[0], lo[1], lo[2], lo[3]};
        ((uint4*)whi)[6144 + t] = qh;
        ((uint4*)wlo)[6144 + t] = ql;
    }
}

// Fused hidden layer. hin holds g = dis*h (bf16, N+1 rows, row N zero).
// Phase A (R14): wave processes 4 rows (one per 16-lane group); lane loads
//   uint4 (16 B) chunks -> one load instr = 4 neighbor rows. Neighbor idx
//   clamped to zero row N beyond each row's padded degree (L1-hot).
// Phase B: MFMA 16x16x32 bf16, W double-pumped (hi+lo), fp32 acc, bias+relu.
// proj=0: store bf16 activations (scaled by dis if scale_out).
// proj=1: h3 -> LDS (u16 stride 136, 16B-aligned rows) -> MFMA projection
//         with pre-swizzled Wout (pwhi/pwlo), write tmpC = dis*(h3 Wout).
__global__ __launch_bounds__(256) void k_fused(const u16* __restrict__ hin,
                                               const u32* __restrict__ whi,
                                               const u32* __restrict__ wlo,
                                               const float* __restrict__ bias,
                                               u16* __restrict__ hout,
                                               const int* __restrict__ rowptr,
                                               const int* __restrict__ csr,
                                               const float* __restrict__ dis,
                                               int N, int scale_out,
                                               int proj,
                                               const u32* __restrict__ pwhi,
                                               const u32* __restrict__ pwlo,
                                               float* __restrict__ tmpC) {
    __shared__ u32 sS[32 * 68];   // phase A/B: stride-65 u32; proj: stride-136 u16
    __shared__ float dS[32];
    int tid = threadIdx.x;
    int wave = tid >> 6;
    int lane = tid & 63;
    int row0 = blockIdx.x * 32;
    const uint4* hin4 = (const uint4*)hin;    // row stride 16 uint4s (256 B)

    // ---- Phase A: 2 quads of 4 rows per wave ----
    int grp = lane >> 4;        // 0..3: which row of the quad
    int sub = lane & 15;        // 16 B chunk within the 256 B row
    #pragma unroll
    for (int jj = 0; jj < 2; ++jj) {
        int rloc = wave * 8 + jj * 4 + grp;
        int row = row0 + rloc;
        bool hR = row < N;
        int ia = 0, rem = 0;
        float dv = 1.f;
        if (hR) {
            ia  = rowptr[row];
            rem = rowptr[row + 1] - ia;   // padded degree (multiple of 4)
            dv  = dis[row];
        }
        // self term initializes the accumulator (row N is the zero row)
        int nself = hR ? row : N;
        uint4 ps = hin4[((u32)nself << 4) + sub];
        float a0 = bf_lo(ps.x), a1 = bf_hi(ps.x);
        float a2 = bf_lo(ps.y), a3 = bf_hi(ps.y);
        float a4 = bf_lo(ps.z), a5 = bf_hi(ps.z);
        float a6 = bf_lo(ps.w), a7 = bf_hi(ps.w);
        // quad-max padded degree (uniform loop across the 4 groups)
        int m = rem;
        m = max(m, __shfl_xor(m, 16));
        m = max(m, __shfl_xor(m, 32));
        const int4* cq = (const int4*)(csr + ia);   // ia is multiple of 4
        for (int k = 0; k < m; k += 8) {
            int4 q0 = cq[(k >> 2)];
            int4 q1 = cq[(k >> 2) + 1];
            // rem is a multiple of 4 -> whole int4 valid or whole invalid
            bool v0 = k < rem;
            bool v1 = (k + 4) < rem;
            int n0 = v0 ? q0.x : N;
            int n1 = v0 ? q0.y : N;
            int n2 = v0 ? q0.z : N;
            int n3 = v0 ? q0.w : N;
            int n4 = v1 ? q1.x : N;
            int n5 = v1 ? q1.y : N;
            int n6 = v1 ? q1.z : N;
            int n7 = v1 ? q1.w : N;
            uint4 p0 = hin4[((u32)n0 << 4) + sub];
            uint4 p1 = hin4[((u32)n1 << 4) + sub];
            uint4 p2 = hin4[((u32)n2 << 4) + sub];
            uint4 p3 = hin4[((u32)n3 << 4) + sub];
            uint4 p4 = hin4[((u32)n4 << 4) + sub];
            uint4 p5 = hin4[((u32)n5 << 4) + sub];
            uint4 p6 = hin4[((u32)n6 << 4) + sub];
            uint4 p7 = hin4[((u32)n7 << 4) + sub];
            a0 += bf_lo(p0.x) + bf_lo(p1.x) + bf_lo(p2.x) + bf_lo(p3.x);
            a1 += bf_hi(p0.x) + bf_hi(p1.x) + bf_hi(p2.x) + bf_hi(p3.x);
            a2 += bf_lo(p0.y) + bf_lo(p1.y) + bf_lo(p2.y) + bf_lo(p3.y);
            a3 += bf_hi(p0.y) + bf_hi(p1.y) + bf_hi(p2.y) + bf_hi(p3.y);
            a4 += bf_lo(p0.z) + bf_lo(p1.z) + bf_lo(p2.z) + bf_lo(p3.z);
            a5 += bf_hi(p0.z) + bf_hi(p1.z) + bf_hi(p2.z) + bf_hi(p3.z);
            a6 += bf_lo(p0.w) + bf_lo(p1.w) + bf_lo(p2.w) + bf_lo(p3.w);
            a7 += bf_hi(p0.w) + bf_hi(p1.w) + bf_hi(p2.w) + bf_hi(p3.w);
            a0 += bf_lo(p4.x) + bf_lo(p5.x) + bf_lo(p6.x) + bf_lo(p7.x);
            a1 += bf_hi(p4.x) + bf_hi(p5.x) + bf_hi(p6.x) + bf_hi(p7.x);
            a2 += bf_lo(p4.y) + bf_lo(p5.y) + bf_lo(p6.y) + bf_lo(p7.y);
            a3 += bf_hi(p4.y) + bf_hi(p5.y) + bf_hi(p6.y) + bf_hi(p7.y);
            a4 += bf_lo(p4.z) + bf_lo(p5.z) + bf_lo(p6.z) + bf_lo(p7.z);
            a5 += bf_hi(p4.z) + bf_hi(p5.z) + bf_hi(p6.z) + bf_hi(p7.z);
            a6 += bf_lo(p4.w) + bf_lo(p5.w) + bf_lo(p6.w) + bf_lo(p7.w);
            a7 += bf_hi(p4.w) + bf_hi(p5.w) + bf_hi(p6.w) + bf_hi(p7.w);
        }
        // scale by dis[row] + pack into the s-tile (word w holds elems 2w,2w+1)
        u32 w0 = (u32)f2bf(dv * a0) | ((u32)f2bf(dv * a1) << 16);
        u32 w1 = (u32)f2bf(dv * a2) | ((u32)f2bf(dv * a3) << 16);
        u32 w2 = (u32)f2bf(dv * a4) | ((u32)f2bf(dv * a5) << 16);
        u32 w3 = (u32)f2bf(dv * a6) | ((u32)f2bf(dv * a7) << 16);
        sS[rloc * 65 + sub * 4 + 0] = w0;
        sS[rloc * 65 + sub * 4 + 1] = w1;
        sS[rloc * 65 + sub * 4 + 2] = w2;
        sS[rloc * 65 + sub * 4 + 3] = w3;
        if (sub == 0) dS[rloc] = dv;
    }
    __syncthreads();

    // ---- Phase B: MFMA. Wave handles col-tiles {2w, 2w+1} x row-tiles {0,1}.
    f32x4 acc[2][2] = {{{0.f,0.f,0.f,0.f},{0.f,0.f,0.f,0.f}},
                       {{0.f,0.f,0.f,0.f},{0.f,0.f,0.f,0.f}}};
    int mA = lane & 15;
    int qA = lane >> 4;
    #pragma unroll
    for (int k0 = 0; k0 < 4; ++k0) {
        union { u32 u[4]; bf16x8 v; } A0, A1;
        int ub = k0 * 16 + qA * 4;
        #pragma unroll
        for (int tt = 0; tt < 4; ++tt) {
            A0.u[tt] = sS[mA * 65 + ub + tt];
            A1.u[tt] = sS[(mA + 16) * 65 + ub + tt];
        }
        #pragma unroll
        for (int ct = 0; ct < 2; ++ct) {
            int ntk = ((2 * wave + ct) * 4 + k0) * 64 + lane;
            union { uint4 q; bf16x8 v; } BH, BL;
            BH.q = ((const uint4*)whi)[ntk];
            BL.q = ((const uint4*)wlo)[ntk];
            acc[0][ct] = __builtin_amdgcn_mfma_f32_16x16x32_bf16(A0.v, BH.v, acc[0][ct], 0, 0, 0);
            acc[0][ct] = __builtin_amdgcn_mfma_f32_16x16x32_bf16(A0.v, BL.v, acc[0][ct], 0, 0, 0);
            acc[1][ct] = __builtin_amdgcn_mfma_f32_16x16x32_bf16(A1.v, BH.v, acc[1][ct], 0, 0, 0);
            acc[1][ct] = __builtin_amdgcn_mfma_f32_16x16x32_bf16(A1.v, BL.v, acc[1][ct], 0, 0, 0);
        }
    }

    if (!proj) {
        // epilogue: D[col=lane&15, row=(lane>>4)*4+reg], bias+relu, bf16 store
        #pragma unroll
        for (int rt = 0; rt < 2; ++rt) {
            #pragma unroll
            for (int ct = 0; ct < 2; ++ct) {
                int col = (2 * wave + ct) * 16 + (lane & 15);
                float bb = bias[col];
                #pragma unroll
                for (int r = 0; r < 4; ++r) {
                    int rloc = rt * 16 + (lane >> 4) * 4 + r;
                    int row = row0 + rloc;
                    if (row < N) {
                        float o = fmaxf(acc[rt][ct][r] + bb, 0.f);
                        if (scale_out) o *= dS[rloc];
                        hout[((u32)row << 7) + col] = f2bf(o);
                    }
                }
            }
        }
    } else {
        // h3 (bias+relu, bf16 — same rounding as the old store) -> LDS stride 136
        __syncthreads();   // all waves done reading sS (phase B complete)
        u16* hS16 = (u16*)sS;   // [32][136], rows 16B-aligned (272B stride)
        #pragma unroll
        for (int rt = 0; rt < 2; ++rt) {
            #pragma unroll
            for (int ct = 0; ct < 2; ++ct) {
                int col = (2 * wave + ct) * 16 + (lane & 15);
                float bb = bias[col];
                #pragma unroll
                for (int r = 0; r < 4; ++r) {
                    int rloc = rt * 16 + (lane >> 4) * 4 + r;
                    hS16[rloc * 136 + col] = f2bf(fmaxf(acc[rt][ct][r] + bb, 0.f));
                }
            }
        }
        __syncthreads();
        // MFMA projection: row-tile = wave (0/1), single padded col-tile.
        if (wave < 2) {
            int m2 = lane & 15;
            int quad = lane >> 4;
            f32x4 a2 = {0.f, 0.f, 0.f, 0.f};
            #pragma unroll
            for (int k0 = 0; k0 < 4; ++k0) {
                bf16x8 Afrag = *(bf16x8*)&hS16[(wave * 16 + m2) * 136 + k0 * 32 + quad * 8];
                union { uint4 q; bf16x8 v; } BH, BL;
                BH.q = ((const uint4*)pwhi)[k0 * 64 + lane];
                BL.q = ((const uint4*)pwlo)[k0 * 64 + lane];
                a2 = __builtin_amdgcn_mfma_f32_16x16x32_bf16(Afrag, BH.v, a2, 0, 0, 0);
                a2 = __builtin_amdgcn_mfma_f32_16x16x32_bf16(Afrag, BL.v, a2, 0, 0, 0);
            }
            #pragma unroll
            for (int r = 0; r < 4; ++r) {
                int rloc = wave * 16 + quad * 4 + r;
                int row = row0 + rloc;
                if (row < N) tmpC[((u32)row << 4) + m2] = a2[r] * dS[rloc];
            }
        }
        if (blockIdx.x == 0 && tid < 16) tmpC[((u32)N << 4) + tid] = 0.f;  // dummy
    }
}

// Block-per-graph: aggregate t' over padded CSR (zero row soaks pads) and
// mean-pool in one pass. 64 node-groups x 16 feature lanes, LDS tree reduce.
__global__ __launch_bounds__(1024) void k_aggpool(const float* __restrict__ tp,
                                                  const int* __restrict__ rowptr,
                                                  const int* __restrict__ csr,
                                                  const float* __restrict__ dis,
                                                  const int* __restrict__ batch,
                                                  const float* __restrict__ bout,
                                                  float* __restrict__ out,
                                                  int N, int C) {
    __shared__ float red[1024];
    int g = blockIdx.x;
    int tid = threadIdx.x;
    int c = tid & 15;
    int rg = tid >> 4;               // 0..63 row-groups
    int lo = 0, hi = N;
    while (lo < hi) { int m = (lo + hi) >> 1; if (batch[m] < g) lo = m + 1; else hi = m; }
    int lb = lo;
    hi = N;
    while (lo < hi) { int m = (lo + hi) >> 1; if (batch[m] <= g) lo = m + 1; else hi = m; }
    int ub = lo;
    const int4* csr4 = (const int4*)csr;
    float pacc = 0.f;
    for (int v = lb + rg; v < ub; v += 64) {
        float acc = tp[((u32)v << 4) + c];      // self term
        int i = rowptr[v], e = rowptr[v + 1];
        for (; i + 8 <= e; i += 8) {
            int4 q0 = csr4[(u32)i >> 2];
            int4 q1 = csr4[((u32)i >> 2) + 1];
            acc += tp[((u32)q0.x << 4) + c] + tp[((u32)q0.y << 4) + c]
                 + tp[((u32)q0.z << 4) + c] + tp[((u32)q0.w << 4) + c]
                 + tp[((u32)q1.x << 4) + c] + tp[((u32)q1.y << 4) + c]
                 + tp[((u32)q1.z << 4) + c] + tp[((u32)q1.w << 4) + c];
        }
        if (i < e) {   // remainder is exactly 4
            int4 q0 = csr4[(u32)i >> 2];
            acc += tp[((u32)q0.x << 4) + c] + tp[((u32)q0.y << 4) + c]
                 + tp[((u32)q0.z << 4) + c] + tp[((u32)q0.w << 4) + c];
        }
        pacc += dis[v] * acc;
    }
    red[tid] = pacc;
    __syncthreads();
    #pragma unroll
    for (int s = 32; s >= 1; s >>= 1) {
        if (rg < s) red[tid] += red[tid + s * 16];
        __syncthreads();
    }
    if (tid < C) {
        float cnt = (float)(ub - lb);
        out[g * C + tid] = (red[tid] + cnt * bout[tid]) / fmaxf(cnt, 1.0f);
    }
}

extern "C" void kernel_launch(void* const* d_in, const int* in_sizes, int n_in,
                              void* d_out, int out_size, void* d_ws, size_t ws_size,
                              hipStream_t stream) {
    const float* x      = (const float*)d_in[0];
    const int*   ei     = (const int*)d_in[1];
    const int*   batch  = (const int*)d_in[2];
    const float* W_init = (const float*)d_in[3];
    const float* b_init = (const float*)d_in[4];
    const float* W_h0   = (const float*)d_in[5];
    const float* b_h0   = (const float*)d_in[6];
    const float* W_h1   = (const float*)d_in[7];
    const float* b_h1   = (const float*)d_in[8];
    const float* W_out  = (const float*)d_in[9];
    const float* b_out  = (const float*)d_in[10];

    int N = in_sizes[0] / 128;
    int E = in_sizes[1] / 2;
    int C = in_sizes[10];
    int G = out_size / C;
    int SH = (N >> SHARD_SHIFT) + 1;     // shards of 4096 rows

    size_t off = 0;
    auto alloc = [&](size_t bytes) -> char* {
        char* p = (char*)d_ws + off;
        off += (bytes + 255) & ~(size_t)255;
        return p;
    };
    u16*   bufX   = (u16*)  alloc((size_t)(N + 1) * 128 * 2);
    u16*   bufA   = (u16*)  alloc((size_t)(N + 1) * 128 * 2);
    u16*   bufB   = (u16*)  alloc((size_t)(N + 1) * 128 * 2);
    float* dis    = (float*)alloc((size_t)N * 4);
    int*   rowptr = (int*)  alloc((size_t)(N + 1) * 4);
    int*   csr    = (int*)  alloc(((size_t)E + 3 * (size_t)N + 8) * 4);
    int*   tsum   = (int*)  alloc((size_t)SCAN_THREADS * 4);
    u32*   whi    = (u32*)  alloc((3 * 2048 + 256) * 16);
    u32*   wlo    = (u32*)  alloc((3 * 2048 + 256) * 16);
    int*   segbase= (int*)  alloc((size_t)N * SH * 4);
    size_t zoff   = off;
    int*   cnt32  = (int*)  alloc((size_t)N * SH * 4);
    size_t zbytes = off - zoff;

    // aliases into dead regions:
    u16*   rank   = (u16*)bufB;      // live between k_count and k_fill, before
                                     // bufB's first write (k_cast zero-row)
    float* tmpC   = (float*)bufX;    // (N+1)x16 fp32; live after bufX is dead

    hipMemsetAsync(cnt32, 0, zbytes, stream);

    const int* rowi = ei;       // edge_index[0] = source
    const int* coli = ei + E;   // edge_index[1] = target

    int eb = (E + 255) / 256;
    k_count<<<eb, 256, 0, stream>>>(coli, rowi, E, cnt32, SH, rank);
    k_scan1<<<SCAN_BLOCKS, 256, 0, stream>>>(cnt32, SH, tsum, N);
    k_scan2<<<1, 1024, 0, stream>>>(tsum);
    k_scan3<<<SCAN_BLOCKS, 256, 0, stream>>>(cnt32, SH, tsum, rowptr, segbase, dis, csr, N);
    k_fill<<<eb, 256, 0, stream>>>(rowi, coli, E, segbase, SH, rank, csr);

    k_wprep4<<<25, 256, 0, stream>>>(W_init, W_h0, W_h1, W_out, whi, wlo, C);

    int cg = ((N + 1) * 32 + 255) / 256;
    k_cast<<<cg, 256, 0, stream>>>(x, dis, bufX, bufA, bufB, N);

    int fb = (N + 31) / 32;

    // hidden layers (activations stored as dis*h except the last)
    k_fused<<<fb, 256, 0, stream>>>(bufX, whi,         wlo,         b_init, bufA, rowptr, csr, dis, N, 1, 0, nullptr, nullptr, nullptr);
    k_fused<<<fb, 256, 0, stream>>>(bufA, whi + 8192,  wlo + 8192,  b_h0,   bufB, rowptr, csr, dis, N, 1, 0, nullptr, nullptr, nullptr);
    // layer 3 + MFMA 128->C projection: writes tmpC = dis*(h3 Wout) directly
    k_fused<<<fb, 256, 0, stream>>>(bufB, whi + 16384, wlo + 16384, b_h1,   bufA, rowptr, csr, dis, N, 0, 1, whi + 24576, wlo + 24576, tmpC);

    // output head: aggregate + pool fused (block per graph, no atomics)
    k_aggpool<<<G, 1024, 0, stream>>>(tmpC, rowptr, csr, dis, batch, b_out, (float*)d_out, N, C);
}

// Round 4
// 477.902 us; speedup vs baseline: 1.1391x; 1.1391x over previous
//
#include <hip/hip_runtime.h>

// ---------------------------------------------------------------------------
// GCN (PyG-style) on MI355X.
//   h = relu(Ahat (h W) + b) x3, then Ahat (h W_out) + b_out, mean-pool.
// R1: hierarchical scan. R2: fusion Ahat(hW)=(Ahat h)W. R3: bf16 activations.
// R4: dis-prescaled activations. R5: padded CSR + paired 16-deep gather.
// R6: MFMA phase B (double-pumped W=Whi+Wlo), rank-based fill.
// R8: no-atomic pooling. R10: proj fused into layer-3.
// R13: projection on MFMA too; aggout+pool merged into k_aggpool.
// R14: phase A 4-rows-per-wave x uint4-per-lane (1 KB/load-instr).
// R15 FAILED (reverted): 2-deep pipeline — MSHR-limited, not ILP-limited.
// R16: shard-ordered CSR (neighbors sorted by src>>12) for L2-window locality.
//     REGRESSION in prep: serial 25-shard loops in strip order made k_scan3
//     96us (2.5% HBM, 0.4% VALU — pure uncoalesced latency).
// R17: prep made coalesced. cnt32/segbase transposed to [SH][N]; new k_deg
//     (row-per-thread, coalesced) computes deg/pdeg/dis; scans run on the
//     single pdeg int per row (R14 cost); new k_segbase (row-per-thread,
//     coalesced planes) does the 25-shard prefix + csr pad writes.
//     k_fused / shard ordering / 1024-thread aggpool unchanged.
// ---------------------------------------------------------------------------

#define SCAN_BLOCKS 64
#define SCAN_THREADS (SCAN_BLOCKS * 256)   // 16384
#define SHARD_SHIFT 12                      // 4096 rows/shard = 1MB of table

typedef unsigned short u16;
typedef unsigned int   u32;
typedef __attribute__((ext_vector_type(8))) short bf16x8;   // 8 bf16 (4 VGPRs)
typedef __attribute__((ext_vector_type(4))) float f32x4;

static __device__ __forceinline__ u16 f2bf(float x) {
    u32 u = __float_as_uint(x);
    u32 r = (u + 0x7fffu + ((u >> 16) & 1u)) >> 16;   // RNE
    return (u16)r;
}
static __device__ __forceinline__ float bf_lo(u32 p) { return __uint_as_float(p << 16); }
static __device__ __forceinline__ float bf_hi(u32 p) { return __uint_as_float(p & 0xffff0000u); }

// rank within (target, source-shard) bucket -> csr comes out shard-sorted.
// cnt32 layout: [SH][N] (transposed for coalesced plane sweeps).
__global__ __launch_bounds__(256) void k_count(const int* __restrict__ col,
                                               const int* __restrict__ row,
                                               int E,
                                               int* __restrict__ cnt32, int N,
                                               u16* __restrict__ rank) {
    int e = blockIdx.x * 256 + threadIdx.x;
    if (e < E) {
        int c = col[e];
        int s = row[e] >> SHARD_SHIFT;
        rank[e] = (u16)atomicAdd(&cnt32[s * N + c], 1);
    }
}

// Row-per-thread: total degree over shard planes (coalesced), pdeg, dis.
__global__ __launch_bounds__(256) void k_deg(const int* __restrict__ cnt32,
                                             int N, int SH,
                                             int* __restrict__ pdeg,
                                             float* __restrict__ dis) {
    int i = blockIdx.x * 256 + threadIdx.x;
    if (i >= N) return;
    int tot = 0;
    for (int q = 0; q < SH; ++q) tot += cnt32[q * N + i];
    pdeg[i] = (tot + 3) & ~3;
    dis[i] = rsqrtf((float)(tot + 1));
}

__global__ __launch_bounds__(256) void k_scan1(const int* __restrict__ pdeg,
                                               int* __restrict__ tsum, int N) {
    int t = blockIdx.x * 256 + threadIdx.x;
    int strip = (N + SCAN_THREADS - 1) / SCAN_THREADS;
    int s0 = t * strip;
    int s1 = s0 + strip; if (s1 > N) s1 = N;
    int s = 0;
    for (int i = s0; i < s1; ++i) s += pdeg[i];
    tsum[t] = s;
}

__global__ __launch_bounds__(1024) void k_scan2(int* __restrict__ tsum) {
    __shared__ int part[1024];
    int t = threadIdx.x;
    int base = t * 16;
    int local[16];
    int s = 0;
    #pragma unroll
    for (int i = 0; i < 16; ++i) { local[i] = tsum[base + i]; s += local[i]; }
    part[t] = s;
    __syncthreads();
    for (int off = 1; off < 1024; off <<= 1) {
        int v = part[t];
        int add = (t >= off) ? part[t - off] : 0;
        __syncthreads();
        part[t] = v + add;
        __syncthreads();
    }
    int run = (t == 0) ? 0 : part[t - 1];
    #pragma unroll
    for (int i = 0; i < 16; ++i) { int c = local[i]; tsum[base + i] = run; run += c; }
}

// Pure rowptr scan over pdeg (R14 cost).
__global__ __launch_bounds__(256) void k_scan3(const int* __restrict__ pdeg,
                                               const int* __restrict__ tsum,
                                               int* __restrict__ rowptr, int N) {
    int t = blockIdx.x * 256 + threadIdx.x;
    int strip = (N + SCAN_THREADS - 1) / SCAN_THREADS;
    int s0 = t * strip;
    int s1 = s0 + strip; if (s1 > N) s1 = N;
    int run = tsum[t];
    for (int i = s0; i < s1; ++i) {
        rowptr[i] = run;
        run += pdeg[i];
    }
    if (t == SCAN_THREADS - 1) rowptr[N] = run;
}

// Row-per-thread: shard prefix -> segbase[q][i] (coalesced planes) + csr pads.
__global__ __launch_bounds__(256) void k_segbase(const int* __restrict__ cnt32,
                                                 const int* __restrict__ rowptr,
                                                 int N, int SH,
                                                 int* __restrict__ segbase,
                                                 int* __restrict__ csr) {
    int i = blockIdx.x * 256 + threadIdx.x;
    if (i >= N) return;
    int rp = rowptr[i];
    int acc = 0;
    for (int q = 0; q < SH; ++q) {
        segbase[q * N + i] = rp + acc;
        acc += cnt32[q * N + i];
    }
    int r = (acc + 3) & ~3;
    for (int p = rp + acc; p < rp + r; ++p) csr[p] = N;   // pads -> zero row
}

// Scatter without atomics: rank captured during k_count (per (col,shard)).
__global__ __launch_bounds__(256) void k_fill(const int* __restrict__ row,
                                              const int* __restrict__ col, int E,
                                              const int* __restrict__ segbase, int N,
                                              const u16* __restrict__ rank,
                                              int* __restrict__ csr) {
    int e = blockIdx.x * 256 + threadIdx.x;
    if (e < E) {
        int c = col[e];
        int src = row[e];
        int s = src >> SHARD_SHIFT;
        csr[segbase[s * N + c] + (int)rank[e]] = src;
    }
}

// fp32 -> bf16 cast pre-scaled by dis[v]; also zeroes dummy row N of all bufs.
__global__ __launch_bounds__(256) void k_cast(const float* __restrict__ src,
                                              const float* __restrict__ dis,
                                              u16* __restrict__ bX,
                                              u16* __restrict__ bA,
                                              u16* __restrict__ bB, int N) {
    int i = blockIdx.x * 256 + threadIdx.x;   // float4-group index over N+1 rows
    int total = (N + 1) * 32;
    if (i >= total) return;
    int v = i >> 5;
    if (v < N) {
        float dv = dis[v];
        float4 val = ((const float4*)src)[i];
        ushort4 o;
        o.x = f2bf(dv * val.x); o.y = f2bf(dv * val.y);
        o.z = f2bf(dv * val.z); o.w = f2bf(dv * val.w);
        ((ushort4*)bX)[i] = o;
    } else {
        ushort4 z = {0, 0, 0, 0};
        ((ushort4*)bX)[i] = z;
        ((ushort4*)bA)[i] = z;
        ((ushort4*)bB)[i] = z;
    }
}

// Pre-swizzle weights into MFMA B-fragment order, split hi+lo bf16.
// Blocks 0..23: the three 128x128 W (8 blocks each). Block 24: Wout 128xC
// zero-padded to 16 cols, stored at uint4 offset 6144.
__global__ __launch_bounds__(256) void k_wprep4(const float* __restrict__ W0,
                                                const float* __restrict__ W1,
                                                const float* __restrict__ W2,
                                                const float* __restrict__ Wo,
                                                u32* __restrict__ whi,
                                                u32* __restrict__ wlo, int C) {
    if (blockIdx.x < 24) {
        int which = blockIdx.x >> 3;
        const float* W = (which == 0) ? W0 : (which == 1) ? W1 : W2;
        int t = (blockIdx.x & 7) * 256 + threadIdx.x;   // 0..2047
        int lane = t & 63;
        int nk = t >> 6;
        int k0 = nk & 3;
        int ntile = nk >> 2;
        int n = ntile * 16 + (lane & 15);
        int kbase = k0 * 32 + (lane >> 4) * 8;
        u32 hi[4], lo[4];
        #pragma unroll
        for (int tt = 0; tt < 4; ++tt) {
            float w0 = W[(kbase + 2 * tt) * 128 + n];
            float w1 = W[(kbase + 2 * tt + 1) * 128 + n];
            u16 h0 = f2bf(w0), h1 = f2bf(w1);
            u16 l0 = f2bf(w0 - __uint_as_float((u32)h0 << 16));
            u16 l1 = f2bf(w1 - __uint_as_float((u32)h1 << 16));
            hi[tt] = (u32)h0 | ((u32)h1 << 16);
            lo[tt] = (u32)l0 | ((u32)l1 << 16);
        }
        uint4 qh = {hi[0], hi[1], hi[2], hi[3]};
        uint4 ql = {lo[0], lo[1], lo[2], lo[3]};
        int base = which * 2048;
        ((uint4*)whi)[base + t] = qh;
        ((uint4*)wlo)[base + t] = ql;
    } else {
        int t = threadIdx.x;       // 0..255 == k0*64 + lane
        int lane = t & 63;
        int k0 = t >> 6;
        int n = lane & 15;
        int kbase = k0 * 32 + (lane >> 4) * 8;
        bool vc = (n < C);
        u32 hi[4], lo[4];
        #pragma unroll
        for (int tt = 0; tt < 4; ++tt) {
            float w0 = vc ? Wo[(kbase + 2 * tt) * C + n] : 0.f;
            float w1 = vc ? Wo[(kbase + 2 * tt + 1) * C + n] : 0.f;
            u16 h0 = f2bf(w0), h1 = f2bf(w1);
            u16 l0 = f2bf(w0 - __uint_as_float((u32)h0 << 16));
            u16 l1 = f2bf(w1 - __uint_as_float((u32)h1 << 16));
            hi[tt] = (u32)h0 | ((u32)h1 << 16);
            lo[tt] = (u32)l0 | ((u32)l1 << 16);
        }
        uint4 qh = {hi[0], hi[1], hi[2], hi[3]};
        uint4 ql = {lo[0], lo[1], lo[2], lo[3]};
        ((uint4*)whi)[6144 + t] = qh;
        ((uint4*)wlo)[6144 + t] = ql;
    }
}

// Fused hidden layer. hin holds g = dis*h (bf16, N+1 rows, row N zero).
// Phase A (R14): wave processes 4 rows (one per 16-lane group); lane loads
//   uint4 (16 B) chunks -> one load instr = 4 neighbor rows. Neighbor idx
//   clamped to zero row N beyond each row's padded degree (L1-hot).
// Phase B: MFMA 16x16x32 bf16, W double-pumped (hi+lo), fp32 acc, bias+relu.
// proj=0: store bf16 activations (scaled by dis if scale_out).
// proj=1: h3 -> LDS (u16 stride 136, 16B-aligned rows) -> MFMA projection
//         with pre-swizzled Wout (pwhi/pwlo), write tmpC = dis*(h3 Wout).
__global__ __launch_bounds__(256) void k_fused(const u16* __restrict__ hin,
                                               const u32* __restrict__ whi,
                                               const u32* __restrict__ wlo,
                                               const float* __restrict__ bias,
                                               u16* __restrict__ hout,
                                               const int* __restrict__ rowptr,
                                               const int* __restrict__ csr,
                                               const float* __restrict__ dis,
                                               int N, int scale_out,
                                               int proj,
                                               const u32* __restrict__ pwhi,
                                               const u32* __restrict__ pwlo,
                                               float* __restrict__ tmpC) {
    __shared__ u32 sS[32 * 68];   // phase A/B: stride-65 u32; proj: stride-136 u16
    __shared__ float dS[32];
    int tid = threadIdx.x;
    int wave = tid >> 6;
    int lane = tid & 63;
    int row0 = blockIdx.x * 32;
    const uint4* hin4 = (const uint4*)hin;    // row stride 16 uint4s (256 B)

    // ---- Phase A: 2 quads of 4 rows per wave ----
    int grp = lane >> 4;        // 0..3: which row of the quad
    int sub = lane & 15;        // 16 B chunk within the 256 B row
    #pragma unroll
    for (int jj = 0; jj < 2; ++jj) {
        int rloc = wave * 8 + jj * 4 + grp;
        int row = row0 + rloc;
        bool hR = row < N;
        int ia = 0, rem = 0;
        float dv = 1.f;
        if (hR) {
            ia  = rowptr[row];
            rem = rowptr[row + 1] - ia;   // padded degree (multiple of 4)
            dv  = dis[row];
        }
        // self term initializes the accumulator (row N is the zero row)
        int nself = hR ? row : N;
        uint4 ps = hin4[((u32)nself << 4) + sub];
        float a0 = bf_lo(ps.x), a1 = bf_hi(ps.x);
        float a2 = bf_lo(ps.y), a3 = bf_hi(ps.y);
        float a4 = bf_lo(ps.z), a5 = bf_hi(ps.z);
        float a6 = bf_lo(ps.w), a7 = bf_hi(ps.w);
        // quad-max padded degree (uniform loop across the 4 groups)
        int m = rem;
        m = max(m, __shfl_xor(m, 16));
        m = max(m, __shfl_xor(m, 32));
        const int4* cq = (const int4*)(csr + ia);   // ia is multiple of 4
        for (int k = 0; k < m; k += 8) {
            int4 q0 = cq[(k >> 2)];
            int4 q1 = cq[(k >> 2) + 1];
            // rem is a multiple of 4 -> whole int4 valid or whole invalid
            bool v0 = k < rem;
            bool v1 = (k + 4) < rem;
            int n0 = v0 ? q0.x : N;
            int n1 = v0 ? q0.y : N;
            int n2 = v0 ? q0.z : N;
            int n3 = v0 ? q0.w : N;
            int n4 = v1 ? q1.x : N;
            int n5 = v1 ? q1.y : N;
            int n6 = v1 ? q1.z : N;
            int n7 = v1 ? q1.w : N;
            uint4 p0 = hin4[((u32)n0 << 4) + sub];
            uint4 p1 = hin4[((u32)n1 << 4) + sub];
            uint4 p2 = hin4[((u32)n2 << 4) + sub];
            uint4 p3 = hin4[((u32)n3 << 4) + sub];
            uint4 p4 = hin4[((u32)n4 << 4) + sub];
            uint4 p5 = hin4[((u32)n5 << 4) + sub];
            uint4 p6 = hin4[((u32)n6 << 4) + sub];
            uint4 p7 = hin4[((u32)n7 << 4) + sub];
            a0 += bf_lo(p0.x) + bf_lo(p1.x) + bf_lo(p2.x) + bf_lo(p3.x);
            a1 += bf_hi(p0.x) + bf_hi(p1.x) + bf_hi(p2.x) + bf_hi(p3.x);
            a2 += bf_lo(p0.y) + bf_lo(p1.y) + bf_lo(p2.y) + bf_lo(p3.y);
            a3 += bf_hi(p0.y) + bf_hi(p1.y) + bf_hi(p2.y) + bf_hi(p3.y);
            a4 += bf_lo(p0.z) + bf_lo(p1.z) + bf_lo(p2.z) + bf_lo(p3.z);
            a5 += bf_hi(p0.z) + bf_hi(p1.z) + bf_hi(p2.z) + bf_hi(p3.z);
            a6 += bf_lo(p0.w) + bf_lo(p1.w) + bf_lo(p2.w) + bf_lo(p3.w);
            a7 += bf_hi(p0.w) + bf_hi(p1.w) + bf_hi(p2.w) + bf_hi(p3.w);
            a0 += bf_lo(p4.x) + bf_lo(p5.x) + bf_lo(p6.x) + bf_lo(p7.x);
            a1 += bf_hi(p4.x) + bf_hi(p5.x) + bf_hi(p6.x) + bf_hi(p7.x);
            a2 += bf_lo(p4.y) + bf_lo(p5.y) + bf_lo(p6.y) + bf_lo(p7.y);
            a3 += bf_hi(p4.y) + bf_hi(p5.y) + bf_hi(p6.y) + bf_hi(p7.y);
            a4 += bf_lo(p4.z) + bf_lo(p5.z) + bf_lo(p6.z) + bf_lo(p7.z);
            a5 += bf_hi(p4.z) + bf_hi(p5.z) + bf_hi(p6.z) + bf_hi(p7.z);
            a6 += bf_lo(p4.w) + bf_lo(p5.w) + bf_lo(p6.w) + bf_lo(p7.w);
            a7 += bf_hi(p4.w) + bf_hi(p5.w) + bf_hi(p6.w) + bf_hi(p7.w);
        }
        // scale by dis[row] + pack into the s-tile (word w holds elems 2w,2w+1)
        u32 w0 = (u32)f2bf(dv * a0) | ((u32)f2bf(dv * a1) << 16);
        u32 w1 = (u32)f2bf(dv * a2) | ((u32)f2bf(dv * a3) << 16);
        u32 w2 = (u32)f2bf(dv * a4) | ((u32)f2bf(dv * a5) << 16);
        u32 w3 = (u32)f2bf(dv * a6) | ((u32)f2bf(dv * a7) << 16);
        sS[rloc * 65 + sub * 4 + 0] = w0;
        sS[rloc * 65 + sub * 4 + 1] = w1;
        sS[rloc * 65 + sub * 4 + 2] = w2;
        sS[rloc * 65 + sub * 4 + 3] = w3;
        if (sub == 0) dS[rloc] = dv;
    }
    __syncthreads();

    // ---- Phase B: MFMA. Wave handles col-tiles {2w, 2w+1} x row-tiles {0,1}.
    f32x4 acc[2][2] = {{{0.f,0.f,0.f,0.f},{0.f,0.f,0.f,0.f}},
                       {{0.f,0.f,0.f,0.f},{0.f,0.f,0.f,0.f}}};
    int mA = lane & 15;
    int qA = lane >> 4;
    #pragma unroll
    for (int k0 = 0; k0 < 4; ++k0) {
        union { u32 u[4]; bf16x8 v; } A0, A1;
        int ub = k0 * 16 + qA * 4;
        #pragma unroll
        for (int tt = 0; tt < 4; ++tt) {
            A0.u[tt] = sS[mA * 65 + ub + tt];
            A1.u[tt] = sS[(mA + 16) * 65 + ub + tt];
        }
        #pragma unroll
        for (int ct = 0; ct < 2; ++ct) {
            int ntk = ((2 * wave + ct) * 4 + k0) * 64 + lane;
            union { uint4 q; bf16x8 v; } BH, BL;
            BH.q = ((const uint4*)whi)[ntk];
            BL.q = ((const uint4*)wlo)[ntk];
            acc[0][ct] = __builtin_amdgcn_mfma_f32_16x16x32_bf16(A0.v, BH.v, acc[0][ct], 0, 0, 0);
            acc[0][ct] = __builtin_amdgcn_mfma_f32_16x16x32_bf16(A0.v, BL.v, acc[0][ct], 0, 0, 0);
            acc[1][ct] = __builtin_amdgcn_mfma_f32_16x16x32_bf16(A1.v, BH.v, acc[1][ct], 0, 0, 0);
            acc[1][ct] = __builtin_amdgcn_mfma_f32_16x16x32_bf16(A1.v, BL.v, acc[1][ct], 0, 0, 0);
        }
    }

    if (!proj) {
        // epilogue: D[col=lane&15, row=(lane>>4)*4+reg], bias+relu, bf16 store
        #pragma unroll
        for (int rt = 0; rt < 2; ++rt) {
            #pragma unroll
            for (int ct = 0; ct < 2; ++ct) {
                int col = (2 * wave + ct) * 16 + (lane & 15);
                float bb = bias[col];
                #pragma unroll
                for (int r = 0; r < 4; ++r) {
                    int rloc = rt * 16 + (lane >> 4) * 4 + r;
                    int row = row0 + rloc;
                    if (row < N) {
                        float o = fmaxf(acc[rt][ct][r] + bb, 0.f);
                        if (scale_out) o *= dS[rloc];
                        hout[((u32)row << 7) + col] = f2bf(o);
                    }
                }
            }
        }
    } else {
        // h3 (bias+relu, bf16 — same rounding as the old store) -> LDS stride 136
        __syncthreads();   // all waves done reading sS (phase B complete)
        u16* hS16 = (u16*)sS;   // [32][136], rows 16B-aligned (272B stride)
        #pragma unroll
        for (int rt = 0; rt < 2; ++rt) {
            #pragma unroll
            for (int ct = 0; ct < 2; ++ct) {
                int col = (2 * wave + ct) * 16 + (lane & 15);
                float bb = bias[col];
                #pragma unroll
                for (int r = 0; r < 4; ++r) {
                    int rloc = rt * 16 + (lane >> 4) * 4 + r;
                    hS16[rloc * 136 + col] = f2bf(fmaxf(acc[rt][ct][r] + bb, 0.f));
                }
            }
        }
        __syncthreads();
        // MFMA projection: row-tile = wave (0/1), single padded col-tile.
        if (wave < 2) {
            int m2 = lane & 15;
            int quad = lane >> 4;
            f32x4 a2 = {0.f, 0.f, 0.f, 0.f};
            #pragma unroll
            for (int k0 = 0; k0 < 4; ++k0) {
                bf16x8 Afrag = *(bf16x8*)&hS16[(wave * 16 + m2) * 136 + k0 * 32 + quad * 8];
                union { uint4 q; bf16x8 v; } BH, BL;
                BH.q = ((const uint4*)pwhi)[k0 * 64 + lane];
                BL.q = ((const uint4*)pwlo)[k0 * 64 + lane];
                a2 = __builtin_amdgcn_mfma_f32_16x16x32_bf16(Afrag, BH.v, a2, 0, 0, 0);
                a2 = __builtin_amdgcn_mfma_f32_16x16x32_bf16(Afrag, BL.v, a2, 0, 0, 0);
            }
            #pragma unroll
            for (int r = 0; r < 4; ++r) {
                int rloc = wave * 16 + quad * 4 + r;
                int row = row0 + rloc;
                if (row < N) tmpC[((u32)row << 4) + m2] = a2[r] * dS[rloc];
            }
        }
        if (blockIdx.x == 0 && tid < 16) tmpC[((u32)N << 4) + tid] = 0.f;  // dummy
    }
}

// Block-per-graph: aggregate t' over padded CSR (zero row soaks pads) and
// mean-pool in one pass. 64 node-groups x 16 feature lanes, LDS tree reduce.
__global__ __launch_bounds__(1024) void k_aggpool(const float* __restrict__ tp,
                                                  const int* __restrict__ rowptr,
                                                  const int* __restrict__ csr,
                                                  const float* __restrict__ dis,
                                                  const int* __restrict__ batch,
                                                  const float* __restrict__ bout,
                                                  float* __restrict__ out,
                                                  int N, int C) {
    __shared__ float red[1024];
    int g = blockIdx.x;
    int tid = threadIdx.x;
    int c = tid & 15;
    int rg = tid >> 4;               // 0..63 row-groups
    int lo = 0, hi = N;
    while (lo < hi) { int m = (lo + hi) >> 1; if (batch[m] < g) lo = m + 1; else hi = m; }
    int lb = lo;
    hi = N;
    while (lo < hi) { int m = (lo + hi) >> 1; if (batch[m] <= g) lo = m + 1; else hi = m; }
    int ub = lo;
    const int4* csr4 = (const int4*)csr;
    float pacc = 0.f;
    for (int v = lb + rg; v < ub; v += 64) {
        float acc = tp[((u32)v << 4) + c];      // self term
        int i = rowptr[v], e = rowptr[v + 1];
        for (; i + 8 <= e; i += 8) {
            int4 q0 = csr4[(u32)i >> 2];
            int4 q1 = csr4[((u32)i >> 2) + 1];
            acc += tp[((u32)q0.x << 4) + c] + tp[((u32)q0.y << 4) + c]
                 + tp[((u32)q0.z << 4) + c] + tp[((u32)q0.w << 4) + c]
                 + tp[((u32)q1.x << 4) + c] + tp[((u32)q1.y << 4) + c]
                 + tp[((u32)q1.z << 4) + c] + tp[((u32)q1.w << 4) + c];
        }
        if (i < e) {   // remainder is exactly 4
            int4 q0 = csr4[(u32)i >> 2];
            acc += tp[((u32)q0.x << 4) + c] + tp[((u32)q0.y << 4) + c]
                 + tp[((u32)q0.z << 4) + c] + tp[((u32)q0.w << 4) + c];
        }
        pacc += dis[v] * acc;
    }
    red[tid] = pacc;
    __syncthreads();
    #pragma unroll
    for (int s = 32; s >= 1; s >>= 1) {
        if (rg < s) red[tid] += red[tid + s * 16];
        __syncthreads();
    }
    if (tid < C) {
        float cnt = (float)(ub - lb);
        out[g * C + tid] = (red[tid] + cnt * bout[tid]) / fmaxf(cnt, 1.0f);
    }
}

extern "C" void kernel_launch(void* const* d_in, const int* in_sizes, int n_in,
                              void* d_out, int out_size, void* d_ws, size_t ws_size,
                              hipStream_t stream) {
    const float* x      = (const float*)d_in[0];
    const int*   ei     = (const int*)d_in[1];
    const int*   batch  = (const int*)d_in[2];
    const float* W_init = (const float*)d_in[3];
    const float* b_init = (const float*)d_in[4];
    const float* W_h0   = (const float*)d_in[5];
    const float* b_h0   = (const float*)d_in[6];
    const float* W_h1   = (const float*)d_in[7];
    const float* b_h1   = (const float*)d_in[8];
    const float* W_out  = (const float*)d_in[9];
    const float* b_out  = (const float*)d_in[10];

    int N = in_sizes[0] / 128;
    int E = in_sizes[1] / 2;
    int C = in_sizes[10];
    int G = out_size / C;
    int SH = (N >> SHARD_SHIFT) + 1;     // shards of 4096 rows

    size_t off = 0;
    auto alloc = [&](size_t bytes) -> char* {
        char* p = (char*)d_ws + off;
        off += (bytes + 255) & ~(size_t)255;
        return p;
    };
    u16*   bufX   = (u16*)  alloc((size_t)(N + 1) * 128 * 2);
    u16*   bufA   = (u16*)  alloc((size_t)(N + 1) * 128 * 2);
    u16*   bufB   = (u16*)  alloc((size_t)(N + 1) * 128 * 2);
    float* dis    = (float*)alloc((size_t)N * 4);
    int*   rowptr = (int*)  alloc((size_t)(N + 1) * 4);
    int*   csr    = (int*)  alloc(((size_t)E + 3 * (size_t)N + 8) * 4);
    int*   tsum   = (int*)  alloc((size_t)SCAN_THREADS * 4);
    int*   pdeg   = (int*)  alloc((size_t)N * 4);
    u32*   whi    = (u32*)  alloc((3 * 2048 + 256) * 16);
    u32*   wlo    = (u32*)  alloc((3 * 2048 + 256) * 16);
    int*   segbase= (int*)  alloc((size_t)N * SH * 4);
    size_t zoff   = off;
    int*   cnt32  = (int*)  alloc((size_t)N * SH * 4);
    size_t zbytes = off - zoff;

    // aliases into dead regions:
    u16*   rank   = (u16*)bufB;      // live between k_count and k_fill, before
                                     // bufB's first write (k_cast zero-row)
    float* tmpC   = (float*)bufX;    // (N+1)x16 fp32; live after bufX is dead

    hipMemsetAsync(cnt32, 0, zbytes, stream);

    const int* rowi = ei;       // edge_index[0] = source
    const int* coli = ei + E;   // edge_index[1] = target

    int eb = (E + 255) / 256;
    int nb = (N + 255) / 256;
    k_count<<<eb, 256, 0, stream>>>(coli, rowi, E, cnt32, N, rank);
    k_deg<<<nb, 256, 0, stream>>>(cnt32, N, SH, pdeg, dis);
    k_scan1<<<SCAN_BLOCKS, 256, 0, stream>>>(pdeg, tsum, N);
    k_scan2<<<1, 1024, 0, stream>>>(tsum);
    k_scan3<<<SCAN_BLOCKS, 256, 0, stream>>>(pdeg, tsum, rowptr, N);
    k_segbase<<<nb, 256, 0, stream>>>(cnt32, rowptr, N, SH, segbase, csr);
    k_fill<<<eb, 256, 0, stream>>>(rowi, coli, E, segbase, N, rank, csr);

    k_wprep4<<<25, 256, 0, stream>>>(W_init, W_h0, W_h1, W_out, whi, wlo, C);

    int cg = ((N + 1) * 32 + 255) / 256;
    k_cast<<<cg, 256, 0, stream>>>(x, dis, bufX, bufA, bufB, N);

    int fb = (N + 31) / 32;

    // hidden layers (activations stored as dis*h except the last)
    k_fused<<<fb, 256, 0, stream>>>(bufX, whi,         wlo,         b_init, bufA, rowptr, csr, dis, N, 1, 0, nullptr, nullptr, nullptr);
    k_fused<<<fb, 256, 0, stream>>>(bufA, whi + 8192,  wlo + 8192,  b_h0,   bufB, rowptr, csr, dis, N, 1, 0, nullptr, nullptr, nullptr);
    // layer 3 + MFMA 128->C projection: writes tmpC = dis*(h3 Wout) directly
    k_fused<<<fb, 256, 0, stream>>>(bufB, whi + 16384, wlo + 16384, b_h1,   bufA, rowptr, csr, dis, N, 0, 1, whi + 24576, wlo + 24576, tmpC);

    // output head: aggregate + pool fused (block per graph, no atomics)
    k_aggpool<<<G, 1024, 0, stream>>>(tmpC, rowptr, csr, dis, batch, b_out, (float*)d_out, N, C);
}

// Round 5
// 438.330 us; speedup vs baseline: 1.2420x; 1.0903x over previous
//
#include <hip/hip_runtime.h>

// ---------------------------------------------------------------------------
// GCN (PyG-style) on MI355X.
//   h = relu(Ahat (h W) + b) x3, then Ahat (h W_out) + b_out, mean-pool.
// R1: hierarchical scan. R2: fusion Ahat(hW)=(Ahat h)W. R3: bf16 activations.
// R4: dis-prescaled activations. R5: padded CSR + paired 16-deep gather.
// R6: MFMA phase B (double-pumped W=Whi+Wlo), rank-based fill.
// R8: no-atomic pooling. R10: proj fused into layer-3.
// R13: projection on MFMA too; aggout+pool merged into k_aggpool.
// R14: phase A 4-rows-per-wave x uint4-per-lane (1 KB/load-instr).
// R15 FAILED (reverted): 2-deep pipeline — MSHR-limited, not ILP-limited.
// R16/R17 FAILED (reverted): shard-ordered CSR — no L2-window locality on a
//     random graph (rows not phase-aligned); k_fused 73->76.5us. Phase A is
//     miss-concurrency x L3-latency capped: structural for random graphs.
// R18: revert to R14 prep. Tail attack: tmpC (=dis*(h3 Wout)) stored bf16 ->
//     aggpool gather table 6.4->3.2MB, fits per-XCD L2 (4MB); gather traffic
//     halves and latency ~600->~200cy. aggpool regrouped 8 lanes/row
//     (row=32B), 128 node-groups x 1024 threads.
// ---------------------------------------------------------------------------

#define SCAN_BLOCKS 64
#define SCAN_THREADS (SCAN_BLOCKS * 256)   // 16384

typedef unsigned short u16;
typedef unsigned int   u32;
typedef __attribute__((ext_vector_type(8))) short bf16x8;   // 8 bf16 (4 VGPRs)
typedef __attribute__((ext_vector_type(4))) float f32x4;

static __device__ __forceinline__ u16 f2bf(float x) {
    u32 u = __float_as_uint(x);
    u32 r = (u + 0x7fffu + ((u >> 16) & 1u)) >> 16;   // RNE
    return (u16)r;
}
static __device__ __forceinline__ float bf_lo(u32 p) { return __uint_as_float(p << 16); }
static __device__ __forceinline__ float bf_hi(u32 p) { return __uint_as_float(p & 0xffff0000u); }

__global__ __launch_bounds__(256) void k_count(const int* __restrict__ col, int E,
                                               int* __restrict__ cnt,
                                               u16* __restrict__ rank) {
    int e = blockIdx.x * 256 + threadIdx.x;
    if (e < E) rank[e] = (u16)atomicAdd(&cnt[col[e]], 1);
}

__global__ __launch_bounds__(256) void k_scan1(const int* __restrict__ cnt,
                                               int* __restrict__ tsum, int N) {
    int t = blockIdx.x * 256 + threadIdx.x;
    int strip = (N + SCAN_THREADS - 1) / SCAN_THREADS;
    int s0 = t * strip;
    int s1 = s0 + strip; if (s1 > N) s1 = N;
    int s = 0;
    for (int i = s0; i < s1; ++i) s += (cnt[i] + 3) & ~3;
    tsum[t] = s;
}

__global__ __launch_bounds__(1024) void k_scan2(int* __restrict__ tsum) {
    __shared__ int part[1024];
    int t = threadIdx.x;
    int base = t * 16;
    int local[16];
    int s = 0;
    #pragma unroll
    for (int i = 0; i < 16; ++i) { local[i] = tsum[base + i]; s += local[i]; }
    part[t] = s;
    __syncthreads();
    for (int off = 1; off < 1024; off <<= 1) {
        int v = part[t];
        int add = (t >= off) ? part[t - off] : 0;
        __syncthreads();
        part[t] = v + add;
        __syncthreads();
    }
    int run = (t == 0) ? 0 : part[t - 1];
    #pragma unroll
    for (int i = 0; i < 16; ++i) { int c = local[i]; tsum[base + i] = run; run += c; }
}

__global__ __launch_bounds__(256) void k_scan3(const int* __restrict__ cnt,
                                               const int* __restrict__ tsum,
                                               int* __restrict__ rowptr,
                                               float* __restrict__ dis,
                                               int* __restrict__ csr, int N) {
    int t = blockIdx.x * 256 + threadIdx.x;
    int strip = (N + SCAN_THREADS - 1) / SCAN_THREADS;
    int s0 = t * strip;
    int s1 = s0 + strip; if (s1 > N) s1 = N;
    int run = tsum[t];
    for (int i = s0; i < s1; ++i) {
        int c = cnt[i];
        int r = (c + 3) & ~3;
        rowptr[i] = run;
        for (int p = run + c; p < run + r; ++p) csr[p] = N;   // pads -> zero row
        run += r;
        dis[i] = rsqrtf((float)(c + 1));
    }
    if (t == SCAN_THREADS - 1) rowptr[N] = run;
}

// Scatter without atomics: rank captured during k_count.
__global__ __launch_bounds__(256) void k_fill(const int* __restrict__ row,
                                              const int* __restrict__ col, int E,
                                              const int* __restrict__ rowptr,
                                              const u16* __restrict__ rank,
                                              int* __restrict__ csr) {
    int e = blockIdx.x * 256 + threadIdx.x;
    if (e < E) {
        int c = col[e];
        csr[rowptr[c] + (int)rank[e]] = row[e];
    }
}

// fp32 -> bf16 cast pre-scaled by dis[v]; also zeroes dummy row N of all bufs.
__global__ __launch_bounds__(256) void k_cast(const float* __restrict__ src,
                                              const float* __restrict__ dis,
                                              u16* __restrict__ bX,
                                              u16* __restrict__ bA,
                                              u16* __restrict__ bB, int N) {
    int i = blockIdx.x * 256 + threadIdx.x;   // float4-group index over N+1 rows
    int total = (N + 1) * 32;
    if (i >= total) return;
    int v = i >> 5;
    if (v < N) {
        float dv = dis[v];
        float4 val = ((const float4*)src)[i];
        ushort4 o;
        o.x = f2bf(dv * val.x); o.y = f2bf(dv * val.y);
        o.z = f2bf(dv * val.z); o.w = f2bf(dv * val.w);
        ((ushort4*)bX)[i] = o;
    } else {
        ushort4 z = {0, 0, 0, 0};
        ((ushort4*)bX)[i] = z;
        ((ushort4*)bA)[i] = z;
        ((ushort4*)bB)[i] = z;
    }
}

// Pre-swizzle weights into MFMA B-fragment order, split hi+lo bf16.
// Blocks 0..23: the three 128x128 W (8 blocks each). Block 24: Wout 128xC
// zero-padded to 16 cols, stored at uint4 offset 6144.
__global__ __launch_bounds__(256) void k_wprep4(const float* __restrict__ W0,
                                                const float* __restrict__ W1,
                                                const float* __restrict__ W2,
                                                const float* __restrict__ Wo,
                                                u32* __restrict__ whi,
                                                u32* __restrict__ wlo, int C) {
    if (blockIdx.x < 24) {
        int which = blockIdx.x >> 3;
        const float* W = (which == 0) ? W0 : (which == 1) ? W1 : W2;
        int t = (blockIdx.x & 7) * 256 + threadIdx.x;   // 0..2047
        int lane = t & 63;
        int nk = t >> 6;
        int k0 = nk & 3;
        int ntile = nk >> 2;
        int n = ntile * 16 + (lane & 15);
        int kbase = k0 * 32 + (lane >> 4) * 8;
        u32 hi[4], lo[4];
        #pragma unroll
        for (int tt = 0; tt < 4; ++tt) {
            float w0 = W[(kbase + 2 * tt) * 128 + n];
            float w1 = W[(kbase + 2 * tt + 1) * 128 + n];
            u16 h0 = f2bf(w0), h1 = f2bf(w1);
            u16 l0 = f2bf(w0 - __uint_as_float((u32)h0 << 16));
            u16 l1 = f2bf(w1 - __uint_as_float((u32)h1 << 16));
            hi[tt] = (u32)h0 | ((u32)h1 << 16);
            lo[tt] = (u32)l0 | ((u32)l1 << 16);
        }
        uint4 qh = {hi[0], hi[1], hi[2], hi[3]};
        uint4 ql = {lo[0], lo[1], lo[2], lo[3]};
        int base = which * 2048;
        ((uint4*)whi)[base + t] = qh;
        ((uint4*)wlo)[base + t] = ql;
    } else {
        int t = threadIdx.x;       // 0..255 == k0*64 + lane
        int lane = t & 63;
        int k0 = t >> 6;
        int n = lane & 15;
        int kbase = k0 * 32 + (lane >> 4) * 8;
        bool vc = (n < C);
        u32 hi[4], lo[4];
        #pragma unroll
        for (int tt = 0; tt < 4; ++tt) {
            float w0 = vc ? Wo[(kbase + 2 * tt) * C + n] : 0.f;
            float w1 = vc ? Wo[(kbase + 2 * tt + 1) * C + n] : 0.f;
            u16 h0 = f2bf(w0), h1 = f2bf(w1);
            u16 l0 = f2bf(w0 - __uint_as_float((u32)h0 << 16));
            u16 l1 = f2bf(w1 - __uint_as_float((u32)h1 << 16));
            hi[tt] = (u32)h0 | ((u32)h1 << 16);
            lo[tt] = (u32)l0 | ((u32)l1 << 16);
        }
        uint4 qh = {hi[0], hi[1], hi[2], hi[3]};
        uint4 ql = {lo[0], lo[1], lo[2], lo[3]};
        ((uint4*)whi)[6144 + t] = qh;
        ((uint4*)wlo)[6144 + t] = ql;
    }
}

// Fused hidden layer. hin holds g = dis*h (bf16, N+1 rows, row N zero).
// Phase A (R14): wave processes 4 rows (one per 16-lane group); lane loads
//   uint4 (16 B) chunks -> one load instr = 4 neighbor rows. Neighbor idx
//   clamped to zero row N beyond each row's padded degree (L1-hot).
// Phase B: MFMA 16x16x32 bf16, W double-pumped (hi+lo), fp32 acc, bias+relu.
// proj=0: store bf16 activations (scaled by dis if scale_out).
// proj=1: h3 -> LDS (u16 stride 136, 16B-aligned rows) -> MFMA projection
//         with pre-swizzled Wout (pwhi/pwlo), write tmpC = bf16 dis*(h3 Wout).
__global__ __launch_bounds__(256) void k_fused(const u16* __restrict__ hin,
                                               const u32* __restrict__ whi,
                                               const u32* __restrict__ wlo,
                                               const float* __restrict__ bias,
                                               u16* __restrict__ hout,
                                               const int* __restrict__ rowptr,
                                               const int* __restrict__ csr,
                                               const float* __restrict__ dis,
                                               int N, int scale_out,
                                               int proj,
                                               const u32* __restrict__ pwhi,
                                               const u32* __restrict__ pwlo,
                                               u16* __restrict__ tmpC) {
    __shared__ u32 sS[32 * 68];   // phase A/B: stride-65 u32; proj: stride-136 u16
    __shared__ float dS[32];
    int tid = threadIdx.x;
    int wave = tid >> 6;
    int lane = tid & 63;
    int row0 = blockIdx.x * 32;
    const uint4* hin4 = (const uint4*)hin;    // row stride 16 uint4s (256 B)

    // ---- Phase A: 2 quads of 4 rows per wave ----
    int grp = lane >> 4;        // 0..3: which row of the quad
    int sub = lane & 15;        // 16 B chunk within the 256 B row
    #pragma unroll
    for (int jj = 0; jj < 2; ++jj) {
        int rloc = wave * 8 + jj * 4 + grp;
        int row = row0 + rloc;
        bool hR = row < N;
        int ia = 0, rem = 0;
        float dv = 1.f;
        if (hR) {
            ia  = rowptr[row];
            rem = rowptr[row + 1] - ia;   // padded degree (multiple of 4)
            dv  = dis[row];
        }
        // self term initializes the accumulator (row N is the zero row)
        int nself = hR ? row : N;
        uint4 ps = hin4[((u32)nself << 4) + sub];
        float a0 = bf_lo(ps.x), a1 = bf_hi(ps.x);
        float a2 = bf_lo(ps.y), a3 = bf_hi(ps.y);
        float a4 = bf_lo(ps.z), a5 = bf_hi(ps.z);
        float a6 = bf_lo(ps.w), a7 = bf_hi(ps.w);
        // quad-max padded degree (uniform loop across the 4 groups)
        int m = rem;
        m = max(m, __shfl_xor(m, 16));
        m = max(m, __shfl_xor(m, 32));
        const int4* cq = (const int4*)(csr + ia);   // ia is multiple of 4
        for (int k = 0; k < m; k += 8) {
            int4 q0 = cq[(k >> 2)];
            int4 q1 = cq[(k >> 2) + 1];
            // rem is a multiple of 4 -> whole int4 valid or whole invalid
            bool v0 = k < rem;
            bool v1 = (k + 4) < rem;
            int n0 = v0 ? q0.x : N;
            int n1 = v0 ? q0.y : N;
            int n2 = v0 ? q0.z : N;
            int n3 = v0 ? q0.w : N;
            int n4 = v1 ? q1.x : N;
            int n5 = v1 ? q1.y : N;
            int n6 = v1 ? q1.z : N;
            int n7 = v1 ? q1.w : N;
            uint4 p0 = hin4[((u32)n0 << 4) + sub];
            uint4 p1 = hin4[((u32)n1 << 4) + sub];
            uint4 p2 = hin4[((u32)n2 << 4) + sub];
            uint4 p3 = hin4[((u32)n3 << 4) + sub];
            uint4 p4 = hin4[((u32)n4 << 4) + sub];
            uint4 p5 = hin4[((u32)n5 << 4) + sub];
            uint4 p6 = hin4[((u32)n6 << 4) + sub];
            uint4 p7 = hin4[((u32)n7 << 4) + sub];
            a0 += bf_lo(p0.x) + bf_lo(p1.x) + bf_lo(p2.x) + bf_lo(p3.x);
            a1 += bf_hi(p0.x) + bf_hi(p1.x) + bf_hi(p2.x) + bf_hi(p3.x);
            a2 += bf_lo(p0.y) + bf_lo(p1.y) + bf_lo(p2.y) + bf_lo(p3.y);
            a3 += bf_hi(p0.y) + bf_hi(p1.y) + bf_hi(p2.y) + bf_hi(p3.y);
            a4 += bf_lo(p0.z) + bf_lo(p1.z) + bf_lo(p2.z) + bf_lo(p3.z);
            a5 += bf_hi(p0.z) + bf_hi(p1.z) + bf_hi(p2.z) + bf_hi(p3.z);
            a6 += bf_lo(p0.w) + bf_lo(p1.w) + bf_lo(p2.w) + bf_lo(p3.w);
            a7 += bf_hi(p0.w) + bf_hi(p1.w) + bf_hi(p2.w) + bf_hi(p3.w);
            a0 += bf_lo(p4.x) + bf_lo(p5.x) + bf_lo(p6.x) + bf_lo(p7.x);
            a1 += bf_hi(p4.x) + bf_hi(p5.x) + bf_hi(p6.x) + bf_hi(p7.x);
            a2 += bf_lo(p4.y) + bf_lo(p5.y) + bf_lo(p6.y) + bf_lo(p7.y);
            a3 += bf_hi(p4.y) + bf_hi(p5.y) + bf_hi(p6.y) + bf_hi(p7.y);
            a4 += bf_lo(p4.z) + bf_lo(p5.z) + bf_lo(p6.z) + bf_lo(p7.z);
            a5 += bf_hi(p4.z) + bf_hi(p5.z) + bf_hi(p6.z) + bf_hi(p7.z);
            a6 += bf_lo(p4.w) + bf_lo(p5.w) + bf_lo(p6.w) + bf_lo(p7.w);
            a7 += bf_hi(p4.w) + bf_hi(p5.w) + bf_hi(p6.w) + bf_hi(p7.w);
        }
        // scale by dis[row] + pack into the s-tile (word w holds elems 2w,2w+1)
        u32 w0 = (u32)f2bf(dv * a0) | ((u32)f2bf(dv * a1) << 16);
        u32 w1 = (u32)f2bf(dv * a2) | ((u32)f2bf(dv * a3) << 16);
        u32 w2 = (u32)f2bf(dv * a4) | ((u32)f2bf(dv * a5) << 16);
        u32 w3 = (u32)f2bf(dv * a6) | ((u32)f2bf(dv * a7) << 16);
        sS[rloc * 65 + sub * 4 + 0] = w0;
        sS[rloc * 65 + sub * 4 + 1] = w1;
        sS[rloc * 65 + sub * 4 + 2] = w2;
        sS[rloc * 65 + sub * 4 + 3] = w3;
        if (sub == 0) dS[rloc] = dv;
    }
    __syncthreads();

    // ---- Phase B: MFMA. Wave handles col-tiles {2w, 2w+1} x row-tiles {0,1}.
    f32x4 acc[2][2] = {{{0.f,0.f,0.f,0.f},{0.f,0.f,0.f,0.f}},
                       {{0.f,0.f,0.f,0.f},{0.f,0.f,0.f,0.f}}};
    int mA = lane & 15;
    int qA = lane >> 4;
    #pragma unroll
    for (int k0 = 0; k0 < 4; ++k0) {
        union { u32 u[4]; bf16x8 v; } A0, A1;
        int ub = k0 * 16 + qA * 4;
        #pragma unroll
        for (int tt = 0; tt < 4; ++tt) {
            A0.u[tt] = sS[mA * 65 + ub + tt];
            A1.u[tt] = sS[(mA + 16) * 65 + ub + tt];
        }
        #pragma unroll
        for (int ct = 0; ct < 2; ++ct) {
            int ntk = ((2 * wave + ct) * 4 + k0) * 64 + lane;
            union { uint4 q; bf16x8 v; } BH, BL;
            BH.q = ((const uint4*)whi)[ntk];
            BL.q = ((const uint4*)wlo)[ntk];
            acc[0][ct] = __builtin_amdgcn_mfma_f32_16x16x32_bf16(A0.v, BH.v, acc[0][ct], 0, 0, 0);
            acc[0][ct] = __builtin_amdgcn_mfma_f32_16x16x32_bf16(A0.v, BL.v, acc[0][ct], 0, 0, 0);
            acc[1][ct] = __builtin_amdgcn_mfma_f32_16x16x32_bf16(A1.v, BH.v, acc[1][ct], 0, 0, 0);
            acc[1][ct] = __builtin_amdgcn_mfma_f32_16x16x32_bf16(A1.v, BL.v, acc[1][ct], 0, 0, 0);
        }
    }

    if (!proj) {
        // epilogue: D[col=lane&15, row=(lane>>4)*4+reg], bias+relu, bf16 store
        #pragma unroll
        for (int rt = 0; rt < 2; ++rt) {
            #pragma unroll
            for (int ct = 0; ct < 2; ++ct) {
                int col = (2 * wave + ct) * 16 + (lane & 15);
                float bb = bias[col];
                #pragma unroll
                for (int r = 0; r < 4; ++r) {
                    int rloc = rt * 16 + (lane >> 4) * 4 + r;
                    int row = row0 + rloc;
                    if (row < N) {
                        float o = fmaxf(acc[rt][ct][r] + bb, 0.f);
                        if (scale_out) o *= dS[rloc];
                        hout[((u32)row << 7) + col] = f2bf(o);
                    }
                }
            }
        }
    } else {
        // h3 (bias+relu, bf16 — same rounding as the old store) -> LDS stride 136
        __syncthreads();   // all waves done reading sS (phase B complete)
        u16* hS16 = (u16*)sS;   // [32][136], rows 16B-aligned (272B stride)
        #pragma unroll
        for (int rt = 0; rt < 2; ++rt) {
            #pragma unroll
            for (int ct = 0; ct < 2; ++ct) {
                int col = (2 * wave + ct) * 16 + (lane & 15);
                float bb = bias[col];
                #pragma unroll
                for (int r = 0; r < 4; ++r) {
                    int rloc = rt * 16 + (lane >> 4) * 4 + r;
                    hS16[rloc * 136 + col] = f2bf(fmaxf(acc[rt][ct][r] + bb, 0.f));
                }
            }
        }
        __syncthreads();
        // MFMA projection: row-tile = wave (0/1), single padded col-tile.
        if (wave < 2) {
            int m2 = lane & 15;
            int quad = lane >> 4;
            f32x4 a2 = {0.f, 0.f, 0.f, 0.f};
            #pragma unroll
            for (int k0 = 0; k0 < 4; ++k0) {
                bf16x8 Afrag = *(bf16x8*)&hS16[(wave * 16 + m2) * 136 + k0 * 32 + quad * 8];
                union { uint4 q; bf16x8 v; } BH, BL;
                BH.q = ((const uint4*)pwhi)[k0 * 64 + lane];
                BL.q = ((const uint4*)pwlo)[k0 * 64 + lane];
                a2 = __builtin_amdgcn_mfma_f32_16x16x32_bf16(Afrag, BH.v, a2, 0, 0, 0);
                a2 = __builtin_amdgcn_mfma_f32_16x16x32_bf16(Afrag, BL.v, a2, 0, 0, 0);
            }
            #pragma unroll
            for (int r = 0; r < 4; ++r) {
                int rloc = wave * 16 + quad * 4 + r;
                int row = row0 + rloc;
                if (row < N) tmpC[((u32)row << 4) + m2] = f2bf(a2[r] * dS[rloc]);
            }
        }
        if (blockIdx.x == 0 && tid < 16) tmpC[((u32)N << 4) + tid] = 0;  // dummy
    }
}

// Block-per-graph: aggregate t' (bf16, 32B rows) over padded CSR (zero row
// soaks pads) and mean-pool in one pass. 128 node-groups x 8 lanes (each lane
// covers 2 channels via packed u32), LDS tree reduce on float2.
__global__ __launch_bounds__(1024) void k_aggpool(const u16* __restrict__ tp,
                                                  const int* __restrict__ rowptr,
                                                  const int* __restrict__ csr,
                                                  const float* __restrict__ dis,
                                                  const int* __restrict__ batch,
                                                  const float* __restrict__ bout,
                                                  float* __restrict__ out,
                                                  int N, int C) {
    __shared__ float2 red[1024];
    int g = blockIdx.x;
    int tid = threadIdx.x;
    int c = tid & 7;                 // u32 index within row (channels 2c,2c+1)
    int rg = tid >> 3;               // 0..127 node-groups
    const u32* tp32 = (const u32*)tp;   // row stride 8 u32 (32 B)
    int lo = 0, hi = N;
    while (lo < hi) { int m = (lo + hi) >> 1; if (batch[m] < g) lo = m + 1; else hi = m; }
    int lb = lo;
    hi = N;
    while (lo < hi) { int m = (lo + hi) >> 1; if (batch[m] <= g) lo = m + 1; else hi = m; }
    int ub = lo;
    const int4* csr4 = (const int4*)csr;
    float px = 0.f, py = 0.f;
    for (int v = lb + rg; v < ub; v += 128) {
        u32 ps = tp32[((u32)v << 3) + c];          // self term
        float ax = bf_lo(ps), ay = bf_hi(ps);
        int i = rowptr[v], e = rowptr[v + 1];
        for (; i + 8 <= e; i += 8) {
            int4 q0 = csr4[(u32)i >> 2];
            int4 q1 = csr4[((u32)i >> 2) + 1];
            u32 p0 = tp32[((u32)q0.x << 3) + c];
            u32 p1 = tp32[((u32)q0.y << 3) + c];
            u32 p2 = tp32[((u32)q0.z << 3) + c];
            u32 p3 = tp32[((u32)q0.w << 3) + c];
            u32 p4 = tp32[((u32)q1.x << 3) + c];
            u32 p5 = tp32[((u32)q1.y << 3) + c];
            u32 p6 = tp32[((u32)q1.z << 3) + c];
            u32 p7 = tp32[((u32)q1.w << 3) + c];
            ax += bf_lo(p0) + bf_lo(p1) + bf_lo(p2) + bf_lo(p3)
                + bf_lo(p4) + bf_lo(p5) + bf_lo(p6) + bf_lo(p7);
            ay += bf_hi(p0) + bf_hi(p1) + bf_hi(p2) + bf_hi(p3)
                + bf_hi(p4) + bf_hi(p5) + bf_hi(p6) + bf_hi(p7);
        }
        if (i < e) {   // remainder is exactly 4
            int4 q0 = csr4[(u32)i >> 2];
            u32 p0 = tp32[((u32)q0.x << 3) + c];
            u32 p1 = tp32[((u32)q0.y << 3) + c];
            u32 p2 = tp32[((u32)q0.z << 3) + c];
            u32 p3 = tp32[((u32)q0.w << 3) + c];
            ax += bf_lo(p0) + bf_lo(p1) + bf_lo(p2) + bf_lo(p3);
            ay += bf_hi(p0) + bf_hi(p1) + bf_hi(p2) + bf_hi(p3);
        }
        float dv = dis[v];
        px += dv * ax;
        py += dv * ay;
    }
    red[tid] = make_float2(px, py);
    __syncthreads();
    #pragma unroll
    for (int s = 64; s >= 1; s >>= 1) {
        if (rg < s) {
            float2 o = red[tid + s * 8];
            red[tid].x += o.x; red[tid].y += o.y;
        }
        __syncthreads();
    }
    if (tid < 8) {
        float cnt = (float)(ub - lb);
        float den = fmaxf(cnt, 1.0f);
        float2 s2 = red[tid];
        int ch0 = 2 * tid, ch1 = 2 * tid + 1;
        if (ch0 < C) out[g * C + ch0] = (s2.x + cnt * bout[ch0]) / den;
        if (ch1 < C) out[g * C + ch1] = (s2.y + cnt * bout[ch1]) / den;
    }
}

extern "C" void kernel_launch(void* const* d_in, const int* in_sizes, int n_in,
                              void* d_out, int out_size, void* d_ws, size_t ws_size,
                              hipStream_t stream) {
    const float* x      = (const float*)d_in[0];
    const int*   ei     = (const int*)d_in[1];
    const int*   batch  = (const int*)d_in[2];
    const float* W_init = (const float*)d_in[3];
    const float* b_init = (const float*)d_in[4];
    const float* W_h0   = (const float*)d_in[5];
    const float* b_h0   = (const float*)d_in[6];
    const float* W_h1   = (const float*)d_in[7];
    const float* b_h1   = (const float*)d_in[8];
    const float* W_out  = (const float*)d_in[9];
    const float* b_out  = (const float*)d_in[10];

    int N = in_sizes[0] / 128;
    int E = in_sizes[1] / 2;
    int C = in_sizes[10];
    int G = out_size / C;

    size_t off = 0;
    auto alloc = [&](size_t bytes) -> char* {
        char* p = (char*)d_ws + off;
        off += (bytes + 255) & ~(size_t)255;
        return p;
    };
    u16*   bufX   = (u16*)  alloc((size_t)(N + 1) * 128 * 2);
    u16*   bufA   = (u16*)  alloc((size_t)(N + 1) * 128 * 2);
    u16*   bufB   = (u16*)  alloc((size_t)(N + 1) * 128 * 2);
    float* dis    = (float*)alloc((size_t)N * 4);
    int*   rowptr = (int*)  alloc((size_t)(N + 1) * 4);
    int*   csr    = (int*)  alloc(((size_t)E + 3 * (size_t)N + 8) * 4);
    int*   tsum   = (int*)  alloc((size_t)SCAN_THREADS * 4);
    u32*   whi    = (u32*)  alloc((3 * 2048 + 256) * 16);
    u32*   wlo    = (u32*)  alloc((3 * 2048 + 256) * 16);
    size_t zoff   = off;
    int*   cnt    = (int*)  alloc((size_t)N * 4);
    size_t zbytes = off - zoff;

    // aliases into dead regions:
    u16*   rank   = (u16*)bufB;      // live between k_count and k_fill, before
                                     // bufB's first write (k_cast zero-row)
    u16*   tmpC   = (u16*)bufX;      // (N+1)x16 bf16; live after bufX is dead

    hipMemsetAsync(cnt, 0, zbytes, stream);

    const int* rowi = ei;       // edge_index[0] = source
    const int* coli = ei + E;   // edge_index[1] = target

    int eb = (E + 255) / 256;
    k_count<<<eb, 256, 0, stream>>>(coli, E, cnt, rank);
    k_scan1<<<SCAN_BLOCKS, 256, 0, stream>>>(cnt, tsum, N);
    k_scan2<<<1, 1024, 0, stream>>>(tsum);
    k_scan3<<<SCAN_BLOCKS, 256, 0, stream>>>(cnt, tsum, rowptr, dis, csr, N);
    k_fill<<<eb, 256, 0, stream>>>(rowi, coli, E, rowptr, rank, csr);

    k_wprep4<<<25, 256, 0, stream>>>(W_init, W_h0, W_h1, W_out, whi, wlo, C);

    int cg = ((N + 1) * 32 + 255) / 256;
    k_cast<<<cg, 256, 0, stream>>>(x, dis, bufX, bufA, bufB, N);

    int fb = (N + 31) / 32;

    // hidden layers (activations stored as dis*h except the last)
    k_fused<<<fb, 256, 0, stream>>>(bufX, whi,         wlo,         b_init, bufA, rowptr, csr, dis, N, 1, 0, nullptr, nullptr, nullptr);
    k_fused<<<fb, 256, 0, stream>>>(bufA, whi + 8192,  wlo + 8192,  b_h0,   bufB, rowptr, csr, dis, N, 1, 0, nullptr, nullptr, nullptr);
    // layer 3 + MFMA 128->C projection: writes tmpC = bf16 dis*(h3 Wout)
    k_fused<<<fb, 256, 0, stream>>>(bufB, whi + 16384, wlo + 16384, b_h1,   bufA, rowptr, csr, dis, N, 0, 1, whi + 24576, wlo + 24576, tmpC);

    // output head: aggregate + pool fused (block per graph, no atomics)
    k_aggpool<<<G, 1024, 0, stream>>>(tmpC, rowptr, csr, dis, batch, b_out, (float*)d_out, N, C);
}